// Round 10
// baseline (2857.874 us; speedup 1.0000x reference)
//
#include <hip/hip_runtime.h>
#include <hip/hip_bf16.h>
#include <math.h>

// Problem dims
constexpr int B_   = 8;
constexpr int T_   = 16;
constexpr int N_   = 196;
constexpr int C_   = 768;
constexpr int H_   = 8;
constexpr int D_   = 96;
constexpr int M_   = 196;    // MEM
constexpr int HID_ = 3072;
constexpr int ROWS_ = B_ * N_;   // 1568 == B_*M_
constexpr int MP_   = 1664;      // ROWS_ padded to multiple of 128 (13*128)

typedef __hip_bfloat16 bf16;
typedef __attribute__((ext_vector_type(8))) short bf16x8;
typedef __attribute__((ext_vector_type(4))) float f32x4;

__device__ __forceinline__ float b2f(bf16 x) { return __bfloat162float(x); }
__device__ __forceinline__ short bf2s(bf16 x) { union { bf16 b; short s; } u; u.b = x; return u.s; }
__device__ __forceinline__ float s2f(short x) { union { bf16 b; short s; } u; u.s = x; return __bfloat162float(u.b); }

#define GL2LDS(g, l) __builtin_amdgcn_global_load_lds( \
    (__attribute__((address_space(1))) void*)(g), \
    (__attribute__((address_space(3))) void*)(l), 16, 0, 0)

// Raw block barrier WITHOUT the __syncthreads vmcnt(0) drain.
__device__ __forceinline__ void hard_barrier() {
    asm volatile("" ::: "memory");
    __builtin_amdgcn_s_barrier();
    asm volatile("" ::: "memory");
}

// POST-MORTEM LOG (kept so later rounds don't repeat):
// - XCD block remaps (r2/r3): cut FETCH exactly as predicted, SLOWER. L3
//   absorbs L2 misses; identity dispatch order wins. IDENTITY MAPPING.
// - c1 K-cut via per-batch ap-bias (r3/r4): ~600us loss. Keep K=1536.
// - Single-buffer + vmcnt(0) drain (r5): occupancy unchanged, slower.
// - 8-wave blocks + BN=64 G1 (r6): occupancy 18->35%, zero gain. TLP at
//   >=2.4 blocks/CU is not the lever; G1 stays BN=128.
// - Triple-buffer (r7): 72KB LDS cut residency 3->2 blocks/CU, slower.
//   DOUBLE-buffer + counted vmcnt is this skeleton's optimum (~443TF).
// - r8 (WIN 2936->2793): ap fused into final/ln via atomics; k into G1.
// - r9 (ln_all hoist + dual-source A, +36us): 38MB cold xln_all reads +
//   upfront LN cost offset the build_cat saving. REVERTED to build_cat.
// - This round: r8 base + p2 split-K=4 (312->624 blocks; p2 was the one
//   dispatch at 1.2 blocks/CU — under-subscription, not the falsified
//   TLP case).

// ---------------- block reduction (256 threads) ----------------
__device__ __forceinline__ float block_reduce_sum256(float v, float* sdata) {
    int tid = threadIdx.x;
    sdata[tid] = v;
    __syncthreads();
    for (int s = 128; s > 0; s >>= 1) {
        if (tid < s) sdata[tid] += sdata[tid + s];
        __syncthreads();
    }
    float r = sdata[0];
    __syncthreads();
    return r;
}

// ---------------- batched weight transpose: W[K,N] fp32 -> Wt[N,K] bf16 ----------------
struct TEnt { const float* W; bf16* Wt; int K; int N; int tiles; };
struct TEnts { TEnt e[8]; };

__global__ __launch_bounds__(256) void transpose_all_kernel(TEnts tds)
{
    __shared__ float tile[32][33];
    int local = blockIdx.x;
    int i = 0;
    while (i < 7 && local >= tds.e[i].tiles) { local -= tds.e[i].tiles; ++i; }
    TEnt g = tds.e[i];
    int ntx = g.N / 32;
    int n0 = (local % ntx) * 32, k0 = (local / ntx) * 32;
    int tx = threadIdx.x & 31, ty = threadIdx.x >> 5;
#pragma unroll
    for (int r = 0; r < 32; r += 8)
        tile[ty + r][tx] = g.W[(size_t)(k0 + ty + r) * g.N + n0 + tx];
    __syncthreads();
#pragma unroll
    for (int r = 0; r < 32; r += 8)
        g.Wt[(size_t)(n0 + ty + r) * g.K + k0 + tx] = __float2bfloat16(tile[tx][ty + r]);
}

// ---------------- elementwise fp32 -> bf16 ----------------
__global__ __launch_bounds__(256) void cvt_kernel(const float* __restrict__ W,
                                                  bf16* __restrict__ o, int n)
{
    int i = blockIdx.x * 256 + threadIdx.x;
    if (i < n) o[i] = __float2bfloat16(W[i]);
}

// ---------------- LN of frame 0 -> mem_bf (bf16) + ap accumulation ----------------
__global__ __launch_bounds__(256) void ln_frame_kernel(
    const float* __restrict__ cur, int t,
    const float* __restrict__ w, const float* __restrict__ bia,
    bf16* __restrict__ mem_bf, float* __restrict__ app)
{
    __shared__ float sdata[256];
    int row = blockIdx.x;
    int b = row / N_, n = row % N_;
    const float* src = cur + (((size_t)b * T_ + t) * N_ + n) * C_;
    float x[3];
    float sum = 0.f, sumsq = 0.f;
#pragma unroll
    for (int i = 0; i < 3; i++) {
        int c = threadIdx.x + i * 256;
        x[i] = src[c];
        sum += x[i]; sumsq += x[i] * x[i];
    }
    sum = block_reduce_sum256(sum, sdata);
    sumsq = block_reduce_sum256(sumsq, sdata);
    float mu = sum * (1.0f / C_);
    float var = sumsq * (1.0f / C_) - mu * mu;
    float rs = rsqrtf(var + 1e-5f);
#pragma unroll
    for (int i = 0; i < 3; i++) {
        int c = threadIdx.x + i * 256;
        bf16 hv = __float2bfloat16((x[i] - mu) * rs * w[c] + bia[c]);
        mem_bf[(size_t)row * C_ + c] = hv;
        atomicAdd(&app[(size_t)b * C_ + c], b2f(hv));   // column sum of stored mem
    }
}

// ---------------- cat[row,0:C]=LN(frame t), cat[row,C:2C]=app/M  (bf16) ----------------
__global__ __launch_bounds__(256) void build_cat_kernel(
    const float* __restrict__ cur, int t,
    const float* __restrict__ w, const float* __restrict__ bia,
    const float* __restrict__ app, bf16* __restrict__ cat)
{
    __shared__ float sdata[256];
    int row = blockIdx.x;
    int b = row / N_, n = row % N_;
    const float* src = cur + (((size_t)b * T_ + t) * N_ + n) * C_;
    float x[3];
    float sum = 0.f, sumsq = 0.f;
#pragma unroll
    for (int i = 0; i < 3; i++) {
        int c = threadIdx.x + i * 256;
        x[i] = src[c];
        sum += x[i]; sumsq += x[i] * x[i];
    }
    sum = block_reduce_sum256(sum, sdata);
    sumsq = block_reduce_sum256(sumsq, sdata);
    float mu = sum * (1.0f / C_);
    float var = sumsq * (1.0f / C_) - mu * mu;
    float rs = rsqrtf(var + 1e-5f);
    bf16* dstrow = cat + (size_t)row * (2 * C_);
#pragma unroll
    for (int i = 0; i < 3; i++) {
        int c = threadIdx.x + i * 256;
        dstrow[c] = __float2bfloat16((x[i] - mu) * rs * w[c] + bia[c]);
        dstrow[C_ + c] = __float2bfloat16(app[(size_t)b * C_ + c] * (1.0f / M_));
    }
}

// ---------------- batched MFMA GEMM, BK=64, XOR-swizzled LDS, pipelined ----------------
// R1's proven config: 256 thr (4 waves), double-buffer, counted vmcnt.
struct GemmDesc {
    const bf16* A; const bf16* W; const float* bias; bf16* out;
    int K; int N; int ymax; int gelu;
};
struct GemmDescs { GemmDesc d[4]; };

template <int BN>
__global__ __launch_bounds__(256) void mfma_gemm_multi(GemmDescs ds)
{
    constexpr int BM = 128;
    constexpr int TI = 4;
    constexpr int TJ = (BN / 2) / 16;
    constexpr int ABYTES = BM * 128;          // 16384
    constexpr int BBYTES = BN * 128;          // 16384 / 8192
    constexpr int AR = ABYTES / 4096;         // 4
    constexpr int BR = BBYTES / 4096;         // 4 / 2
    constexpr int NL = AR + BR;
    __shared__ short As[2 * BM * 64];
    __shared__ short Bs[2 * BN * 64];

    GemmDesc g = ds.d[blockIdx.z];
    if ((int)blockIdx.y >= g.ymax) return;

    int tid = threadIdx.x;
    int wid = tid >> 6;
    int lane = tid & 63;
    int quad = lane >> 4, l15 = lane & 15;
    int row0 = blockIdx.x * BM;
    int col0 = blockIdx.y * BN;
    int wm = (wid >> 1) * 64;
    int wn = (wid & 1) * (BN / 2);

    f32x4 acc[TI][TJ] = {};

    const char* Ab = (const char*)g.A;
    const char* Wb = (const char*)g.W;
    const size_t Kb = (size_t)g.K * 2;
    const int base = wid * 1024;

    auto stage = [&](int k0, int sel) {
        char* Ad = (char*)As + sel * ABYTES;
        char* Bd = (char*)Bs + sel * BBYTES;
#pragma unroll
        for (int r = 0; r < AR; r++) {
            int o = r * 4096 + base + lane * 16;
            int row = o >> 7, cs = (o >> 4) & 7;
            int kc = cs ^ (row & 7);
            GL2LDS(Ab + (size_t)(row0 + row) * Kb + (size_t)k0 * 2 + kc * 16, Ad + o);
        }
#pragma unroll
        for (int r = 0; r < BR; r++) {
            int o = r * 4096 + base + lane * 16;
            int row = o >> 7, cs = (o >> 4) & 7;
            int kc = cs ^ (row & 7);
            GL2LDS(Wb + (size_t)(col0 + row) * Kb + (size_t)k0 * 2 + kc * 16, Bd + o);
        }
    };

    const int nk = g.K / 64;
    stage(0, 0);
    for (int ki = 0; ki < nk; ki++) {
        int sel = ki & 1;
        if (ki + 1 < nk) {
            stage((ki + 1) * 64, sel ^ 1);
            asm volatile("s_waitcnt vmcnt(%0)" :: "n"(NL) : "memory");
        } else {
            asm volatile("s_waitcnt vmcnt(0)" ::: "memory");
        }
        hard_barrier();
        const bf16x8* Av = (const bf16x8*)(As + sel * BM * 64);
        const bf16x8* Bv = (const bf16x8*)(Bs + sel * BN * 64);
        bf16x8 af[TI][2], bfr[TJ][2];
#pragma unroll
        for (int i = 0; i < TI; i++) {
            int r = wm + i * 16 + l15;
#pragma unroll
            for (int hh = 0; hh < 2; hh++)
                af[i][hh] = Av[r * 8 + ((hh * 4 + quad) ^ (r & 7))];
        }
#pragma unroll
        for (int j = 0; j < TJ; j++) {
            int r = wn + j * 16 + l15;
#pragma unroll
            for (int hh = 0; hh < 2; hh++)
                bfr[j][hh] = Bv[r * 8 + ((hh * 4 + quad) ^ (r & 7))];
        }
#pragma unroll
        for (int hh = 0; hh < 2; hh++)
#pragma unroll
            for (int i = 0; i < TI; i++)
#pragma unroll
                for (int j = 0; j < TJ; j++)
                    acc[i][j] = __builtin_amdgcn_mfma_f32_16x16x32_bf16(
                        af[i][hh], bfr[j][hh], acc[i][j], 0, 0, 0);
        hard_barrier();
    }

    // epilogue: C/D layout col=lane&15, row=quad*4+reg
#pragma unroll
    for (int i = 0; i < TI; i++) {
        int gr = row0 + wm + i * 16 + quad * 4;
#pragma unroll
        for (int j = 0; j < TJ; j++) {
            int gc = col0 + wn + j * 16 + l15;
            float bv = g.bias ? g.bias[gc] : 0.0f;
#pragma unroll
            for (int r = 0; r < 4; r++) {
                float v = acc[i][j][r] + bv;
                if (g.gelu) v = 0.5f * v * (1.0f + erff(v * 0.7071067811865475f));
                g.out[(size_t)(gr + r) * g.N + gc] = __float2bfloat16(v);
            }
        }
    }
}

// ---------------- split-K MFMA GEMM for p2: part[z][MP_,768] fp32, nsplit-way ----------------
__global__ __launch_bounds__(256) void mfma_gemm_splitk(
    const bf16* __restrict__ A, const bf16* __restrict__ Wt,
    float* __restrict__ part, int K, int nsplit)
{
    constexpr int BM = 128;
    constexpr int BN = 64;
    constexpr int TI = 4;
    constexpr int TJ = 2;
    constexpr int ABYTES = BM * 128, BBYTES = BN * 128;
    constexpr int AR = 4, BR = 2, NL = 6;
    __shared__ short As[2 * BM * 64];
    __shared__ short Bs[2 * BN * 64];

    int tid = threadIdx.x;
    int wid = tid >> 6;
    int lane = tid & 63;
    int quad = lane >> 4, l15 = lane & 15;
    int row0 = blockIdx.x * BM;
    int col0 = blockIdx.y * BN;
    int wm = (wid >> 1) * 64;
    int wn = (wid & 1) * 32;
    int kh = K / nsplit;
    int kbeg = blockIdx.z * kh;

    f32x4 acc[TI][TJ] = {};
    const char* Ab = (const char*)A;
    const char* Wb = (const char*)Wt;
    const size_t Kb = (size_t)K * 2;
    const int base = wid * 1024;

    auto stage = [&](int k0, int sel) {
        char* Ad = (char*)As + sel * ABYTES;
        char* Bd = (char*)Bs + sel * BBYTES;
#pragma unroll
        for (int r = 0; r < AR; r++) {
            int o = r * 4096 + base + lane * 16;
            int row = o >> 7, cs = (o >> 4) & 7;
            int kc = cs ^ (row & 7);
            GL2LDS(Ab + (size_t)(row0 + row) * Kb + (size_t)k0 * 2 + kc * 16, Ad + o);
        }
#pragma unroll
        for (int r = 0; r < BR; r++) {
            int o = r * 4096 + base + lane * 16;
            int row = o >> 7, cs = (o >> 4) & 7;
            int kc = cs ^ (row & 7);
            GL2LDS(Wb + (size_t)(col0 + row) * Kb + (size_t)k0 * 2 + kc * 16, Bd + o);
        }
    };

    const int nk = kh / 64;
    stage(kbeg, 0);
    for (int ki = 0; ki < nk; ki++) {
        int sel = ki & 1;
        if (ki + 1 < nk) {
            stage(kbeg + (ki + 1) * 64, sel ^ 1);
            asm volatile("s_waitcnt vmcnt(%0)" :: "n"(NL) : "memory");
        } else {
            asm volatile("s_waitcnt vmcnt(0)" ::: "memory");
        }
        hard_barrier();
        const bf16x8* Av = (const bf16x8*)(As + sel * BM * 64);
        const bf16x8* Bv = (const bf16x8*)(Bs + sel * BN * 64);
        bf16x8 af[TI][2], bfr[TJ][2];
#pragma unroll
        for (int i = 0; i < TI; i++) {
            int r = wm + i * 16 + l15;
#pragma unroll
            for (int hh = 0; hh < 2; hh++)
                af[i][hh] = Av[r * 8 + ((hh * 4 + quad) ^ (r & 7))];
        }
#pragma unroll
        for (int j = 0; j < TJ; j++) {
            int r = wn + j * 16 + l15;
#pragma unroll
            for (int hh = 0; hh < 2; hh++)
                bfr[j][hh] = Bv[r * 8 + ((hh * 4 + quad) ^ (r & 7))];
        }
#pragma unroll
        for (int hh = 0; hh < 2; hh++)
#pragma unroll
            for (int i = 0; i < TI; i++)
#pragma unroll
                for (int j = 0; j < TJ; j++)
                    acc[i][j] = __builtin_amdgcn_mfma_f32_16x16x32_bf16(
                        af[i][hh], bfr[j][hh], acc[i][j], 0, 0, 0);
        hard_barrier();
    }

    float* outp = part + (size_t)blockIdx.z * MP_ * C_;
#pragma unroll
    for (int i = 0; i < TI; i++) {
        int gr = row0 + wm + i * 16 + quad * 4;
#pragma unroll
        for (int j = 0; j < TJ; j++) {
            int gc = col0 + wn + j * 16 + l15;
#pragma unroll
            for (int r = 0; r < 4; r++)
                outp[(size_t)(gr + r) * C_ + gc] = acc[i][j][r];
        }
    }
}

// ---------------- b2q[n] = q_b[n] + sum_j c_b2[j] * W2q_t[n,j]  (block per n) ----------------
__global__ __launch_bounds__(256) void b2q_kernel(
    const float* __restrict__ c_b2, const float* __restrict__ q_b,
    const bf16* __restrict__ W2q_t, float* __restrict__ b2q)
{
    __shared__ float sdata[256];
    int n = blockIdx.x;
    const bf16* row = W2q_t + (size_t)n * HID_;
    float s = 0.f;
    for (int j = threadIdx.x; j < HID_; j += 256) s += c_b2[j] * b2f(row[j]);
    s = block_reduce_sum256(s, sdata);
    if (threadIdx.x == 0) b2q[n] = s + q_b[n];
}

// ---------------- fused MFMA attention + pool + gate ----------------
__global__ __launch_bounds__(512) void attn_mfma_kernel(
    const bf16* __restrict__ q, const bf16* __restrict__ k,
    const bf16* __restrict__ cg, bf16* __restrict__ cbuf,
    float* __restrict__ gate)
{
    constexpr int KS = 104;   // K/Q LDS row stride (bf16 elems)
    constexpr int PSS = 40;   // P/CGt LDS row stride
    __shared__ short Ks[64 * KS];
    __shared__ short Qs[32 * KS];
    __shared__ short CGt[96 * PSS];
    __shared__ short Ph[64 * PSS];
    __shared__ short Pl[64 * PSS];
    __shared__ float gred[8][64];

    const int mt = blockIdx.x, h = blockIdx.y, b = blockIdx.z;
    const int m0 = (mt < 3) ? mt * 64 : (M_ - 64);   // 0,64,128,132
    const int tid = threadIdx.x;
    const int w = tid >> 6, lane = tid & 63;
    const int quad = lane >> 4, l15 = lane & 15;
    const int wm = w >> 1;     // m-tile (16 rows) for S^T and PV
    const int wh = w & 1;      // n-tile for S^T / d-half (48) for PV
    const float scale = 0.10206207261596575f; // 96^-0.5

    const bf16* qp = q  + (size_t)b * N_ * C_ + h * D_;
    const bf16* kp = k  + (size_t)b * M_ * C_ + h * D_;
    const bf16* cp = cg + (size_t)b * N_ * C_ + h * D_;

    // stage K rows m0..m0+63 (all valid; 768 x 16B)
    for (int idx = tid; idx < 64 * 12; idx += 512) {
        int r = idx / 12, c = idx % 12;
        *(bf16x8*)(Ks + r * KS + c * 8) =
            *(const bf16x8*)(kp + (size_t)(m0 + r) * C_ + c * 8);
    }

    f32x4 acc[3] = {};
    float gacc = 0.f;

    const bf16x8 ZEROV = {0, 0, 0, 0, 0, 0, 0, 0};
    bf16x8 qv = ZEROV, cgv = ZEROV;
    const bool active = tid < 32 * 12;                 // 384 loader threads
    const int qrow = tid / 12, qcol = (tid % 12) * 8;  // Q: row-major 16B
    const int cgn = tid & 31, cgd = (tid >> 5) * 8;    // CG: gather for transpose

    auto issue = [&](int n0) {
        if (!active) return;
        int nq = n0 + qrow;
        qv = (nq < N_) ? *(const bf16x8*)(qp + (size_t)nq * C_ + qcol) : ZEROV;
        int nc = n0 + cgn;
        cgv = (nc < N_) ? *(const bf16x8*)(cp + (size_t)nc * C_ + cgd) : ZEROV;
    };
    auto stage = [&]() {
        if (!active) return;
        *(bf16x8*)(Qs + qrow * KS + qcol) = qv;
#pragma unroll
        for (int i = 0; i < 8; i++) CGt[(cgd + i) * PSS + cgn] = cgv[i];
    };

    issue(0);
    for (int nt = 0; nt < 7; nt++) {
        stage();
        __syncthreads();                       // staged tiles visible
        if (nt < 6) issue((nt + 1) * 32);      // prefetch next chunk (T14)

        // S^T tile [16m x 16n], contraction over D=96 (3 mfma k-steps)
        f32x4 s4 = {};
#pragma unroll
        for (int kk = 0; kk < 3; kk++) {
            bf16x8 af = *(const bf16x8*)(Ks + (wm * 16 + l15) * KS + kk * 32 + quad * 8);
            bf16x8 bq = *(const bf16x8*)(Qs + (wh * 16 + l15) * KS + kk * 32 + quad * 8);
            s4 = __builtin_amdgcn_mfma_f32_16x16x32_bf16(af, bq, s4, 0, 0, 0);
        }
        // sigmoid -> hi/lo bf16 split -> LDS (zero padded n so gate/PV unaffected)
        const int nglob = nt * 32 + wh * 16 + l15;
#pragma unroll
        for (int r = 0; r < 4; r++) {
            float p = (nglob < N_) ? 1.f / (1.f + expf(-s4[r] * scale)) : 0.f;
            bf16 hb = __float2bfloat16(p);
            bf16 lb = __float2bfloat16(p - __bfloat162float(hb));
            int po = (wm * 16 + quad * 4 + r) * PSS + wh * 16 + l15;
            Ph[po] = bf2s(hb);
            Pl[po] = bf2s(lb);
        }
        __syncthreads();                       // P complete

        // gate partial: thread (seg=w, m=lane) sums 4 n-cols (hi+lo)
        {
            const short* ph = Ph + lane * PSS + w * 4;
            const short* pl = Pl + lane * PSS + w * 4;
#pragma unroll
            for (int u = 0; u < 4; u++) gacc += s2f(ph[u]) + s2f(pl[u]);
        }
        // PV: acc[m-tile, d] += P^T · CG  (A = P rows, B = CGt rows)
        bf16x8 pa = *(const bf16x8*)(Ph + (wm * 16 + l15) * PSS + quad * 8);
        bf16x8 pb = *(const bf16x8*)(Pl + (wm * 16 + l15) * PSS + quad * 8);
#pragma unroll
        for (int dt = 0; dt < 3; dt++) {
            bf16x8 bcg = *(const bf16x8*)(CGt + (wh * 48 + dt * 16 + l15) * PSS + quad * 8);
            acc[dt] = __builtin_amdgcn_mfma_f32_16x16x32_bf16(pa, bcg, acc[dt], 0, 0, 0);
            acc[dt] = __builtin_amdgcn_mfma_f32_16x16x32_bf16(pb, bcg, acc[dt], 0, 0, 0);
        }
        __syncthreads();                       // PV done before next stage
    }

    // epilogue: C/D layout col=lane&15, row=quad*4+reg
#pragma unroll
    for (int dt = 0; dt < 3; dt++)
#pragma unroll
        for (int r = 0; r < 4; r++) {
            int m = m0 + wm * 16 + quad * 4 + r;
            cbuf[((size_t)b * M_ + m) * C_ + h * D_ + wh * 48 + dt * 16 + l15] =
                __float2bfloat16(acc[dt][r]);
        }
    gred[w][lane] = gacc;
    __syncthreads();
    if (tid < 64) {
        float g = 0.f;
#pragma unroll
        for (int s = 0; s < 8; s++) g += gred[s][tid];
        gate[((size_t)b * H_ + h) * M_ + m0 + tid] = 1.f - g * (1.0f / N_);
    }
}

// ---------------- new_mem = LN(sum(part)+bias + gate*memh) -> mem_bf (+ ap, + d_out) ----------------
__global__ __launch_bounds__(256) void final_kernel(
    const float* __restrict__ part, int nsplit, const float* __restrict__ p_b2,
    const float* __restrict__ gate, const bf16* __restrict__ memh,
    const float* __restrict__ w, const float* __restrict__ bia,
    bf16* __restrict__ mem_bf, float* __restrict__ app, float* __restrict__ outp)
{
    __shared__ float sdata[256];
    int row = blockIdx.x;
    int b = row / M_, m = row % M_;
    float x[3];
    float sum = 0.f, sumsq = 0.f;
#pragma unroll
    for (int i = 0; i < 3; i++) {
        int c = threadIdx.x + i * 256;
        int h = c / D_;
        float v = p_b2[c]
                + gate[(b * H_ + h) * M_ + m] * b2f(memh[(size_t)row * C_ + c]);
        for (int z = 0; z < nsplit; z++)
            v += part[(size_t)z * MP_ * C_ + (size_t)row * C_ + c];
        x[i] = v;
        sum += v; sumsq += v * v;
    }
    sum = block_reduce_sum256(sum, sdata);
    sumsq = block_reduce_sum256(sumsq, sdata);
    float mu = sum * (1.0f / C_);
    float var = sumsq * (1.0f / C_) - mu * mu;
    float rs = rsqrtf(var + 1e-5f);
#pragma unroll
    for (int i = 0; i < 3; i++) {
        int c = threadIdx.x + i * 256;
        float v = (x[i] - mu) * rs * w[c] + bia[c];
        bf16 hv = __float2bfloat16(v);
        mem_bf[(size_t)row * C_ + c] = hv;
        atomicAdd(&app[(size_t)b * C_ + c], b2f(hv));   // ap for next step
        if (outp) outp[(size_t)row * C_ + c] = v;
    }
}

extern "C" void kernel_launch(void* const* d_in, const int* in_sizes, int n_in,
                              void* d_out, int out_size, void* d_ws, size_t ws_size,
                              hipStream_t stream)
{
    const float* cur_fea = (const float*)d_in[0];
    const float* n1w = (const float*)d_in[1];
    const float* n1b = (const float*)d_in[2];
    const float* n2w = (const float*)d_in[3];
    const float* n2b = (const float*)d_in[4];
    const float* c_w1 = (const float*)d_in[5];
    const float* c_b1 = (const float*)d_in[6];
    const float* c_w2 = (const float*)d_in[7];
    const float* c_b2 = (const float*)d_in[8];
    const float* m_w1 = (const float*)d_in[9];
    const float* m_b1 = (const float*)d_in[10];
    const float* m_w2 = (const float*)d_in[11];
    const float* m_b2 = (const float*)d_in[12];
    const float* p_w1 = (const float*)d_in[13];
    const float* p_b1 = (const float*)d_in[14];
    const float* p_w2 = (const float*)d_in[15];
    const float* p_b2 = (const float*)d_in[16];
    const float* q_w = (const float*)d_in[17];
    const float* q_b = (const float*)d_in[18];
    const float* k_w = (const float*)d_in[19];
    const float* k_b = (const float*)d_in[20];

    // ---- workspace carve (256B-aligned) ----
    size_t off = 0;
    char* base = (char*)d_ws;
    auto carve = [&](size_t bytes) -> char* {
        char* r = base + off;
        off += (bytes + 255) & ~(size_t)255;
        return r;
    };
    bf16* cw1t = (bf16*)carve((size_t)HID_ * (2 * C_) * 2);
    bf16* cw2t = (bf16*)carve((size_t)C_ * HID_ * 2);
    bf16* mw1t = (bf16*)carve((size_t)HID_ * C_ * 2);
    bf16* mw2t = (bf16*)carve((size_t)C_ * HID_ * 2);
    bf16* pw1t = (bf16*)carve((size_t)HID_ * C_ * 2);
    bf16* pw2t = (bf16*)carve((size_t)C_ * HID_ * 2);
    bf16* qwt  = (bf16*)carve((size_t)C_ * C_ * 2);
    bf16* kwt  = (bf16*)carve((size_t)C_ * C_ * 2);
    bf16* mem_bf = (bf16*)carve((size_t)MP_ * C_ * 2);
    char* catreg = carve((size_t)MP_ * 2 * C_ * 2);           // cat; later qb|kb
    bf16* cat = (bf16*)catreg;
    bf16* qb  = (bf16*)catreg;                                // alias (cat dead after G1)
    bf16* kb  = (bf16*)catreg + (size_t)MP_ * C_;             // alias (fallback k-out)
    bf16* hid_c = (bf16*)carve((size_t)MP_ * HID_ * 2);       // c1/p1 out; cw2nt temp pre-loop
    char* hidm_reg = carve((size_t)MP_ * HID_ * 2);           // m1 out; p2 partials (fallback)
    bf16*  hid_m = (bf16*)hidm_reg;
    bf16* cg    = (bf16*)carve((size_t)MP_ * C_ * 2);
    bf16* cbuf  = (bf16*)carve((size_t)MP_ * C_ * 2);
    bf16* memh  = (bf16*)carve((size_t)MP_ * C_ * 2);
    float* app  = (float*)carve((size_t)B_ * C_ * 4);         // column sums of mem
    float* gateb = (float*)carve((size_t)B_ * H_ * M_ * 4);
    float* b2qb  = (float*)carve((size_t)C_ * 4);
    bf16* W2q_t = (bf16*)carve((size_t)C_ * HID_ * 2);
    const bool fuse_q = (off <= ws_size);
    bf16* kb2  = (bf16*)carve((size_t)MP_ * C_ * 2);          // dedicated k-out
    const bool fuse_k = (off <= ws_size);
    float* part4 = (float*)carve((size_t)4 * MP_ * C_ * 4);   // 20.4MB split-K=4 partials
    const bool sk4 = (off <= ws_size);
    float* part = sk4 ? part4 : (float*)hidm_reg;
    const int nsplit = sk4 ? 4 : 2;

    const dim3 blk(256);

    // ---- weight convert + transpose (single batched launch) ----
    {
        TEnts tds;
        tds.e[0] = { c_w1, cw1t, 2 * C_, HID_, (HID_ / 32) * ((2 * C_) / 32) };  // 4608
        tds.e[1] = { c_w2, cw2t, HID_, C_, (C_ / 32) * (HID_ / 32) };            // 2304
        tds.e[2] = { m_w1, mw1t, C_, HID_, (HID_ / 32) * (C_ / 32) };
        tds.e[3] = { m_w2, mw2t, HID_, C_, (C_ / 32) * (HID_ / 32) };
        tds.e[4] = { p_w1, pw1t, C_, HID_, (HID_ / 32) * (C_ / 32) };
        tds.e[5] = { p_w2, pw2t, HID_, C_, (C_ / 32) * (HID_ / 32) };
        tds.e[6] = { q_w, qwt, C_, C_, (C_ / 32) * (C_ / 32) };                  // 576
        tds.e[7] = { k_w, kwt, C_, C_, (C_ / 32) * (C_ / 32) };
        int total = 4608 + 2304 * 5 + 576 * 2;  // 17280
        transpose_all_kernel<<<total, blk, 0, stream>>>(tds);
    }

    if (fuse_q) {
        // W2q_t[n,j] = (c_w2 @ q_w)[j,n]: out = A @ Wt^T, A=qwt[768,768], Wt=cvt(c_w2)[3072,768]
        bf16* cw2nt = hid_c;   // temp, pre-loop only
        cvt_kernel<<<(HID_ * C_ + 255) / 256, blk, 0, stream>>>(c_w2, cw2nt, HID_ * C_);
        GemmDescs ds;
        ds.d[0] = { qwt, cw2nt, nullptr, W2q_t, C_, HID_, HID_ / 128, 0 };
        ds.d[1] = ds.d[0]; ds.d[2] = ds.d[0]; ds.d[3] = ds.d[0];
        mfma_gemm_multi<128><<<dim3(C_ / 128, HID_ / 128, 1), blk, 0, stream>>>(ds);
        b2q_kernel<<<C_, blk, 0, stream>>>(c_b2, q_b, W2q_t, b2qb);
    }

    // ---- init memory = LN(frame 0), with fused ap accumulation ----
    hipMemsetAsync(app, 0, (size_t)B_ * C_ * 4, stream);
    ln_frame_kernel<<<ROWS_, blk, 0, stream>>>(cur_fea, 0, n1w, n1b, mem_bf, app);

    for (int t = 1; t < T_; t++) {
        build_cat_kernel<<<ROWS_, blk, 0, stream>>>(cur_fea, t, n1w, n1b, app, cat);
        hipMemsetAsync(app, 0, (size_t)B_ * C_ * 4, stream);   // consumed; reset for final

        // G1: c1 + m1 (+ k when kb2 fits — k only needs mem_bf; dedicated
        // buffer avoids the cat-alias race). BN=128, dbuf: the proven config.
        {
            GemmDescs ds;
            ds.d[0] = { cat,    cw1t, c_b1, hid_c, 2 * C_, HID_, HID_ / 128, 1 };
            ds.d[1] = { mem_bf, mw1t, m_b1, hid_m, C_,     HID_, HID_ / 128, 1 };
            ds.d[2] = { mem_bf, kwt,  k_b,  kb2,   C_,     C_,   C_ / 128,   0 };
            ds.d[3] = ds.d[0];
            mfma_gemm_multi<128><<<dim3(MP_ / 128, HID_ / 128, fuse_k ? 3 : 2),
                                   blk, 0, stream>>>(ds);
        }
        // G2: c2 + m2 (+ k fallback) + fused q. cat dead after G1.
        {
            GemmDescs ds;
            int z = 0;
            ds.d[z++] = { hid_c,  cw2t, c_b2, cg,   HID_, C_, C_ / 64, 0 };
            ds.d[z++] = { hid_m,  mw2t, m_b2, memh, HID_, C_, C_ / 64, 0 };
            if (!fuse_k) ds.d[z++] = { mem_bf, kwt, k_b, kb, C_, C_, C_ / 64, 0 };
            if (fuse_q)  ds.d[z++] = { hid_c, W2q_t, b2qb, qb, HID_, C_, C_ / 64, 0 };
            for (int f = z; f < 4; f++) ds.d[f] = ds.d[0];
            mfma_gemm_multi<64><<<dim3(MP_ / 128, C_ / 64, z), blk, 0, stream>>>(ds);
        }
        if (!fuse_q) {
            GemmDescs ds;
            ds.d[0] = { cg, qwt, q_b, qb, C_, C_, C_ / 64, 0 };
            ds.d[1] = ds.d[0]; ds.d[2] = ds.d[0]; ds.d[3] = ds.d[0];
            mfma_gemm_multi<64><<<dim3(MP_ / 128, C_ / 64, 1), blk, 0, stream>>>(ds);
        }
        // fused MFMA attention + pool + gate (256 blocks, 8 waves)
        attn_mfma_kernel<<<dim3(4, H_, B_), dim3(512), 0, stream>>>(
            qb, fuse_k ? kb2 : kb, cg, cbuf, gateb);
        // p1 (BN=64: 624 blocks) into hid_c
        {
            GemmDescs ds;
            ds.d[0] = { cbuf, pw1t, p_b1, hid_c, C_, HID_, HID_ / 64, 1 };
            ds.d[1] = ds.d[0]; ds.d[2] = ds.d[0]; ds.d[3] = ds.d[0];
            mfma_gemm_multi<64><<<dim3(MP_ / 128, HID_ / 64, 1), blk, 0, stream>>>(ds);
        }
        // p2 split-K (4-way when part4 fits: 624 blocks = full chip; was 312)
        mfma_gemm_splitk<<<dim3(MP_ / 128, C_ / 64, nsplit), blk, 0, stream>>>(
            hid_c, pw2t, part, HID_, nsplit);
        // residual gate + LN -> new mem (+ fused ap accumulation)
        final_kernel<<<ROWS_, blk, 0, stream>>>(part, nsplit, p_b2, gateb, memh, n2w, n2b,
                                                mem_bf, app,
                                                (t == T_ - 1) ? (float*)d_out : nullptr);
    }
}

// Round 11
// 2773.518 us; speedup vs baseline: 1.0304x; 1.0304x over previous
//
#include <hip/hip_runtime.h>
#include <hip/hip_bf16.h>
#include <math.h>

// Problem dims
constexpr int B_   = 8;
constexpr int T_   = 16;
constexpr int N_   = 196;
constexpr int C_   = 768;
constexpr int H_   = 8;
constexpr int D_   = 96;
constexpr int M_   = 196;    // MEM
constexpr int HID_ = 3072;
constexpr int ROWS_ = B_ * N_;   // 1568 == B_*M_
constexpr int MP_   = 1664;      // ROWS_ padded to multiple of 128 (13*128)

typedef __hip_bfloat16 bf16;
typedef __attribute__((ext_vector_type(8))) short bf16x8;
typedef __attribute__((ext_vector_type(4))) float f32x4;

__device__ __forceinline__ float b2f(bf16 x) { return __bfloat162float(x); }
__device__ __forceinline__ short bf2s(bf16 x) { union { bf16 b; short s; } u; u.b = x; return u.s; }
__device__ __forceinline__ float s2f(short x) { union { bf16 b; short s; } u; u.s = x; return __bfloat162float(u.b); }

#define GL2LDS(g, l) __builtin_amdgcn_global_load_lds( \
    (__attribute__((address_space(1))) void*)(g), \
    (__attribute__((address_space(3))) void*)(l), 16, 0, 0)

// Raw block barrier WITHOUT the __syncthreads vmcnt(0) drain.
__device__ __forceinline__ void hard_barrier() {
    asm volatile("" ::: "memory");
    __builtin_amdgcn_s_barrier();
    asm volatile("" ::: "memory");
}

// POST-MORTEM LOG (kept so later rounds don't repeat):
// - XCD block remaps (r2/r3): cut FETCH exactly as predicted, SLOWER. L3
//   absorbs L2 misses; identity dispatch order wins. IDENTITY MAPPING.
// - c1 K-cut via per-batch ap-bias (r3/r4): ~600us loss. Keep K=1536.
// - Single-buffer + vmcnt(0) drain (r5): occupancy unchanged, slower.
// - 8-wave blocks + BN=64 G1 (r6): occupancy 18->35%, zero gain.
// - Triple-buffer (r7): LDS 72KB cut residency 3->2 blocks/CU, slower.
//   DOUBLE-buffer + counted vmcnt is this skeleton's optimum (~443TF).
// - r8 (WIN 2936->2793): ap fused into final/ln via atomics; k into G1.
// - r9 (ln_all hoist, +36us): cold 38MB xln_all reads offset the saving.
// - r10 (p2 split-K=4, +65us): doubled partials traffic + halved per-block
//   K; under-subscription was NOT p2's binding constraint. nsplit=2.
// - This round: exact r8 + double-buffered app (build_cat zeroes the next
//   buffer in-kernel; kills the per-step memset dispatch).

// ---------------- block reduction (256 threads) ----------------
__device__ __forceinline__ float block_reduce_sum256(float v, float* sdata) {
    int tid = threadIdx.x;
    sdata[tid] = v;
    __syncthreads();
    for (int s = 128; s > 0; s >>= 1) {
        if (tid < s) sdata[tid] += sdata[tid + s];
        __syncthreads();
    }
    float r = sdata[0];
    __syncthreads();
    return r;
}

// ---------------- batched weight transpose: W[K,N] fp32 -> Wt[N,K] bf16 ----------------
struct TEnt { const float* W; bf16* Wt; int K; int N; int tiles; };
struct TEnts { TEnt e[8]; };

__global__ __launch_bounds__(256) void transpose_all_kernel(TEnts tds)
{
    __shared__ float tile[32][33];
    int local = blockIdx.x;
    int i = 0;
    while (i < 7 && local >= tds.e[i].tiles) { local -= tds.e[i].tiles; ++i; }
    TEnt g = tds.e[i];
    int ntx = g.N / 32;
    int n0 = (local % ntx) * 32, k0 = (local / ntx) * 32;
    int tx = threadIdx.x & 31, ty = threadIdx.x >> 5;
#pragma unroll
    for (int r = 0; r < 32; r += 8)
        tile[ty + r][tx] = g.W[(size_t)(k0 + ty + r) * g.N + n0 + tx];
    __syncthreads();
#pragma unroll
    for (int r = 0; r < 32; r += 8)
        g.Wt[(size_t)(n0 + ty + r) * g.K + k0 + tx] = __float2bfloat16(tile[tx][ty + r]);
}

// ---------------- elementwise fp32 -> bf16 ----------------
__global__ __launch_bounds__(256) void cvt_kernel(const float* __restrict__ W,
                                                  bf16* __restrict__ o, int n)
{
    int i = blockIdx.x * 256 + threadIdx.x;
    if (i < n) o[i] = __float2bfloat16(W[i]);
}

// ---------------- LN of frame 0 -> mem_bf (bf16) + ap accumulation ----------------
__global__ __launch_bounds__(256) void ln_frame_kernel(
    const float* __restrict__ cur, int t,
    const float* __restrict__ w, const float* __restrict__ bia,
    bf16* __restrict__ mem_bf, float* __restrict__ app)
{
    __shared__ float sdata[256];
    int row = blockIdx.x;
    int b = row / N_, n = row % N_;
    const float* src = cur + (((size_t)b * T_ + t) * N_ + n) * C_;
    float x[3];
    float sum = 0.f, sumsq = 0.f;
#pragma unroll
    for (int i = 0; i < 3; i++) {
        int c = threadIdx.x + i * 256;
        x[i] = src[c];
        sum += x[i]; sumsq += x[i] * x[i];
    }
    sum = block_reduce_sum256(sum, sdata);
    sumsq = block_reduce_sum256(sumsq, sdata);
    float mu = sum * (1.0f / C_);
    float var = sumsq * (1.0f / C_) - mu * mu;
    float rs = rsqrtf(var + 1e-5f);
#pragma unroll
    for (int i = 0; i < 3; i++) {
        int c = threadIdx.x + i * 256;
        bf16 hv = __float2bfloat16((x[i] - mu) * rs * w[c] + bia[c]);
        mem_bf[(size_t)row * C_ + c] = hv;
        atomicAdd(&app[(size_t)b * C_ + c], b2f(hv));   // column sum of stored mem
    }
}

// ---------------- cat[row,0:C]=LN(frame t), cat[row,C:2C]=app/M; zero app_nxt ----------------
__global__ __launch_bounds__(256) void build_cat_kernel(
    const float* __restrict__ cur, int t,
    const float* __restrict__ w, const float* __restrict__ bia,
    const float* __restrict__ app, float* __restrict__ app_nxt,
    bf16* __restrict__ cat)
{
    __shared__ float sdata[256];
    int row = blockIdx.x;
    int b = row / N_, n = row % N_;
    const float* src = cur + (((size_t)b * T_ + t) * N_ + n) * C_;
    // blocks 0..7 zero the NEXT app buffer (the one final(t) accumulates into)
    if (row < B_) {
#pragma unroll
        for (int i = 0; i < 3; i++)
            app_nxt[(size_t)row * C_ + threadIdx.x + i * 256] = 0.f;
    }
    float x[3];
    float sum = 0.f, sumsq = 0.f;
#pragma unroll
    for (int i = 0; i < 3; i++) {
        int c = threadIdx.x + i * 256;
        x[i] = src[c];
        sum += x[i]; sumsq += x[i] * x[i];
    }
    sum = block_reduce_sum256(sum, sdata);
    sumsq = block_reduce_sum256(sumsq, sdata);
    float mu = sum * (1.0f / C_);
    float var = sumsq * (1.0f / C_) - mu * mu;
    float rs = rsqrtf(var + 1e-5f);
    bf16* dstrow = cat + (size_t)row * (2 * C_);
#pragma unroll
    for (int i = 0; i < 3; i++) {
        int c = threadIdx.x + i * 256;
        dstrow[c] = __float2bfloat16((x[i] - mu) * rs * w[c] + bia[c]);
        dstrow[C_ + c] = __float2bfloat16(app[(size_t)b * C_ + c] * (1.0f / M_));
    }
}

// ---------------- batched MFMA GEMM, BK=64, XOR-swizzled LDS, pipelined ----------------
// R1's proven config: 256 thr (4 waves), double-buffer, counted vmcnt.
struct GemmDesc {
    const bf16* A; const bf16* W; const float* bias; bf16* out;
    int K; int N; int ymax; int gelu;
};
struct GemmDescs { GemmDesc d[4]; };

template <int BN>
__global__ __launch_bounds__(256) void mfma_gemm_multi(GemmDescs ds)
{
    constexpr int BM = 128;
    constexpr int TI = 4;
    constexpr int TJ = (BN / 2) / 16;
    constexpr int ABYTES = BM * 128;          // 16384
    constexpr int BBYTES = BN * 128;          // 16384 / 8192
    constexpr int AR = ABYTES / 4096;         // 4
    constexpr int BR = BBYTES / 4096;         // 4 / 2
    constexpr int NL = AR + BR;
    __shared__ short As[2 * BM * 64];
    __shared__ short Bs[2 * BN * 64];

    GemmDesc g = ds.d[blockIdx.z];
    if ((int)blockIdx.y >= g.ymax) return;

    int tid = threadIdx.x;
    int wid = tid >> 6;
    int lane = tid & 63;
    int quad = lane >> 4, l15 = lane & 15;
    int row0 = blockIdx.x * BM;
    int col0 = blockIdx.y * BN;
    int wm = (wid >> 1) * 64;
    int wn = (wid & 1) * (BN / 2);

    f32x4 acc[TI][TJ] = {};

    const char* Ab = (const char*)g.A;
    const char* Wb = (const char*)g.W;
    const size_t Kb = (size_t)g.K * 2;
    const int base = wid * 1024;

    auto stage = [&](int k0, int sel) {
        char* Ad = (char*)As + sel * ABYTES;
        char* Bd = (char*)Bs + sel * BBYTES;
#pragma unroll
        for (int r = 0; r < AR; r++) {
            int o = r * 4096 + base + lane * 16;
            int row = o >> 7, cs = (o >> 4) & 7;
            int kc = cs ^ (row & 7);
            GL2LDS(Ab + (size_t)(row0 + row) * Kb + (size_t)k0 * 2 + kc * 16, Ad + o);
        }
#pragma unroll
        for (int r = 0; r < BR; r++) {
            int o = r * 4096 + base + lane * 16;
            int row = o >> 7, cs = (o >> 4) & 7;
            int kc = cs ^ (row & 7);
            GL2LDS(Wb + (size_t)(col0 + row) * Kb + (size_t)k0 * 2 + kc * 16, Bd + o);
        }
    };

    const int nk = g.K / 64;
    stage(0, 0);
    for (int ki = 0; ki < nk; ki++) {
        int sel = ki & 1;
        if (ki + 1 < nk) {
            stage((ki + 1) * 64, sel ^ 1);
            asm volatile("s_waitcnt vmcnt(%0)" :: "n"(NL) : "memory");
        } else {
            asm volatile("s_waitcnt vmcnt(0)" ::: "memory");
        }
        hard_barrier();
        const bf16x8* Av = (const bf16x8*)(As + sel * BM * 64);
        const bf16x8* Bv = (const bf16x8*)(Bs + sel * BN * 64);
        bf16x8 af[TI][2], bfr[TJ][2];
#pragma unroll
        for (int i = 0; i < TI; i++) {
            int r = wm + i * 16 + l15;
#pragma unroll
            for (int hh = 0; hh < 2; hh++)
                af[i][hh] = Av[r * 8 + ((hh * 4 + quad) ^ (r & 7))];
        }
#pragma unroll
        for (int j = 0; j < TJ; j++) {
            int r = wn + j * 16 + l15;
#pragma unroll
            for (int hh = 0; hh < 2; hh++)
                bfr[j][hh] = Bv[r * 8 + ((hh * 4 + quad) ^ (r & 7))];
        }
#pragma unroll
        for (int hh = 0; hh < 2; hh++)
#pragma unroll
            for (int i = 0; i < TI; i++)
#pragma unroll
                for (int j = 0; j < TJ; j++)
                    acc[i][j] = __builtin_amdgcn_mfma_f32_16x16x32_bf16(
                        af[i][hh], bfr[j][hh], acc[i][j], 0, 0, 0);
        hard_barrier();
    }

    // epilogue: C/D layout col=lane&15, row=quad*4+reg
#pragma unroll
    for (int i = 0; i < TI; i++) {
        int gr = row0 + wm + i * 16 + quad * 4;
#pragma unroll
        for (int j = 0; j < TJ; j++) {
            int gc = col0 + wn + j * 16 + l15;
            float bv = g.bias ? g.bias[gc] : 0.0f;
#pragma unroll
            for (int r = 0; r < 4; r++) {
                float v = acc[i][j][r] + bv;
                if (g.gelu) v = 0.5f * v * (1.0f + erff(v * 0.7071067811865475f));
                g.out[(size_t)(gr + r) * g.N + gc] = __float2bfloat16(v);
            }
        }
    }
}

// ---------------- split-K MFMA GEMM for p2 (BK=64, swizzled): part[z][MP_,768] fp32 ----------------
__global__ __launch_bounds__(256) void mfma_gemm_splitk(
    const bf16* __restrict__ A, const bf16* __restrict__ Wt,
    float* __restrict__ part, int K)
{
    constexpr int BM = 128;
    constexpr int BN = 64;
    constexpr int TI = 4;
    constexpr int TJ = 2;
    constexpr int ABYTES = BM * 128, BBYTES = BN * 128;
    constexpr int AR = 4, BR = 2, NL = 6;
    __shared__ short As[2 * BM * 64];
    __shared__ short Bs[2 * BN * 64];

    int tid = threadIdx.x;
    int wid = tid >> 6;
    int lane = tid & 63;
    int quad = lane >> 4, l15 = lane & 15;
    int row0 = blockIdx.x * BM;
    int col0 = blockIdx.y * BN;
    int wm = (wid >> 1) * 64;
    int wn = (wid & 1) * 32;
    int kh = K >> 1;
    int kbeg = blockIdx.z * kh;

    f32x4 acc[TI][TJ] = {};
    const char* Ab = (const char*)A;
    const char* Wb = (const char*)Wt;
    const size_t Kb = (size_t)K * 2;
    const int base = wid * 1024;

    auto stage = [&](int k0, int sel) {
        char* Ad = (char*)As + sel * ABYTES;
        char* Bd = (char*)Bs + sel * BBYTES;
#pragma unroll
        for (int r = 0; r < AR; r++) {
            int o = r * 4096 + base + lane * 16;
            int row = o >> 7, cs = (o >> 4) & 7;
            int kc = cs ^ (row & 7);
            GL2LDS(Ab + (size_t)(row0 + row) * Kb + (size_t)k0 * 2 + kc * 16, Ad + o);
        }
#pragma unroll
        for (int r = 0; r < BR; r++) {
            int o = r * 4096 + base + lane * 16;
            int row = o >> 7, cs = (o >> 4) & 7;
            int kc = cs ^ (row & 7);
            GL2LDS(Wb + (size_t)(col0 + row) * Kb + (size_t)k0 * 2 + kc * 16, Bd + o);
        }
    };

    const int nk = kh / 64;
    stage(kbeg, 0);
    for (int ki = 0; ki < nk; ki++) {
        int sel = ki & 1;
        if (ki + 1 < nk) {
            stage(kbeg + (ki + 1) * 64, sel ^ 1);
            asm volatile("s_waitcnt vmcnt(%0)" :: "n"(NL) : "memory");
        } else {
            asm volatile("s_waitcnt vmcnt(0)" ::: "memory");
        }
        hard_barrier();
        const bf16x8* Av = (const bf16x8*)(As + sel * BM * 64);
        const bf16x8* Bv = (const bf16x8*)(Bs + sel * BN * 64);
        bf16x8 af[TI][2], bfr[TJ][2];
#pragma unroll
        for (int i = 0; i < TI; i++) {
            int r = wm + i * 16 + l15;
#pragma unroll
            for (int hh = 0; hh < 2; hh++)
                af[i][hh] = Av[r * 8 + ((hh * 4 + quad) ^ (r & 7))];
        }
#pragma unroll
        for (int j = 0; j < TJ; j++) {
            int r = wn + j * 16 + l15;
#pragma unroll
            for (int hh = 0; hh < 2; hh++)
                bfr[j][hh] = Bv[r * 8 + ((hh * 4 + quad) ^ (r & 7))];
        }
#pragma unroll
        for (int hh = 0; hh < 2; hh++)
#pragma unroll
            for (int i = 0; i < TI; i++)
#pragma unroll
                for (int j = 0; j < TJ; j++)
                    acc[i][j] = __builtin_amdgcn_mfma_f32_16x16x32_bf16(
                        af[i][hh], bfr[j][hh], acc[i][j], 0, 0, 0);
        hard_barrier();
    }

    float* outp = part + (size_t)blockIdx.z * MP_ * C_;
#pragma unroll
    for (int i = 0; i < TI; i++) {
        int gr = row0 + wm + i * 16 + quad * 4;
#pragma unroll
        for (int j = 0; j < TJ; j++) {
            int gc = col0 + wn + j * 16 + l15;
#pragma unroll
            for (int r = 0; r < 4; r++)
                outp[(size_t)(gr + r) * C_ + gc] = acc[i][j][r];
        }
    }
}

// ---------------- b2q[n] = q_b[n] + sum_j c_b2[j] * W2q_t[n,j]  (block per n) ----------------
__global__ __launch_bounds__(256) void b2q_kernel(
    const float* __restrict__ c_b2, const float* __restrict__ q_b,
    const bf16* __restrict__ W2q_t, float* __restrict__ b2q)
{
    __shared__ float sdata[256];
    int n = blockIdx.x;
    const bf16* row = W2q_t + (size_t)n * HID_;
    float s = 0.f;
    for (int j = threadIdx.x; j < HID_; j += 256) s += c_b2[j] * b2f(row[j]);
    s = block_reduce_sum256(s, sdata);
    if (threadIdx.x == 0) b2q[n] = s + q_b[n];
}

// ---------------- fused MFMA attention + pool + gate ----------------
__global__ __launch_bounds__(512) void attn_mfma_kernel(
    const bf16* __restrict__ q, const bf16* __restrict__ k,
    const bf16* __restrict__ cg, bf16* __restrict__ cbuf,
    float* __restrict__ gate)
{
    constexpr int KS = 104;   // K/Q LDS row stride (bf16 elems)
    constexpr int PSS = 40;   // P/CGt LDS row stride
    __shared__ short Ks[64 * KS];
    __shared__ short Qs[32 * KS];
    __shared__ short CGt[96 * PSS];
    __shared__ short Ph[64 * PSS];
    __shared__ short Pl[64 * PSS];
    __shared__ float gred[8][64];

    const int mt = blockIdx.x, h = blockIdx.y, b = blockIdx.z;
    const int m0 = (mt < 3) ? mt * 64 : (M_ - 64);   // 0,64,128,132
    const int tid = threadIdx.x;
    const int w = tid >> 6, lane = tid & 63;
    const int quad = lane >> 4, l15 = lane & 15;
    const int wm = w >> 1;     // m-tile (16 rows) for S^T and PV
    const int wh = w & 1;      // n-tile for S^T / d-half (48) for PV
    const float scale = 0.10206207261596575f; // 96^-0.5

    const bf16* qp = q  + (size_t)b * N_ * C_ + h * D_;
    const bf16* kp = k  + (size_t)b * M_ * C_ + h * D_;
    const bf16* cp = cg + (size_t)b * N_ * C_ + h * D_;

    // stage K rows m0..m0+63 (all valid; 768 x 16B)
    for (int idx = tid; idx < 64 * 12; idx += 512) {
        int r = idx / 12, c = idx % 12;
        *(bf16x8*)(Ks + r * KS + c * 8) =
            *(const bf16x8*)(kp + (size_t)(m0 + r) * C_ + c * 8);
    }

    f32x4 acc[3] = {};
    float gacc = 0.f;

    const bf16x8 ZEROV = {0, 0, 0, 0, 0, 0, 0, 0};
    bf16x8 qv = ZEROV, cgv = ZEROV;
    const bool active = tid < 32 * 12;                 // 384 loader threads
    const int qrow = tid / 12, qcol = (tid % 12) * 8;  // Q: row-major 16B
    const int cgn = tid & 31, cgd = (tid >> 5) * 8;    // CG: gather for transpose

    auto issue = [&](int n0) {
        if (!active) return;
        int nq = n0 + qrow;
        qv = (nq < N_) ? *(const bf16x8*)(qp + (size_t)nq * C_ + qcol) : ZEROV;
        int nc = n0 + cgn;
        cgv = (nc < N_) ? *(const bf16x8*)(cp + (size_t)nc * C_ + cgd) : ZEROV;
    };
    auto stage = [&]() {
        if (!active) return;
        *(bf16x8*)(Qs + qrow * KS + qcol) = qv;
#pragma unroll
        for (int i = 0; i < 8; i++) CGt[(cgd + i) * PSS + cgn] = cgv[i];
    };

    issue(0);
    for (int nt = 0; nt < 7; nt++) {
        stage();
        __syncthreads();                       // staged tiles visible
        if (nt < 6) issue((nt + 1) * 32);      // prefetch next chunk (T14)

        // S^T tile [16m x 16n], contraction over D=96 (3 mfma k-steps)
        f32x4 s4 = {};
#pragma unroll
        for (int kk = 0; kk < 3; kk++) {
            bf16x8 af = *(const bf16x8*)(Ks + (wm * 16 + l15) * KS + kk * 32 + quad * 8);
            bf16x8 bq = *(const bf16x8*)(Qs + (wh * 16 + l15) * KS + kk * 32 + quad * 8);
            s4 = __builtin_amdgcn_mfma_f32_16x16x32_bf16(af, bq, s4, 0, 0, 0);
        }
        // sigmoid -> hi/lo bf16 split -> LDS (zero padded n so gate/PV unaffected)
        const int nglob = nt * 32 + wh * 16 + l15;
#pragma unroll
        for (int r = 0; r < 4; r++) {
            float p = (nglob < N_) ? 1.f / (1.f + expf(-s4[r] * scale)) : 0.f;
            bf16 hb = __float2bfloat16(p);
            bf16 lb = __float2bfloat16(p - __bfloat162float(hb));
            int po = (wm * 16 + quad * 4 + r) * PSS + wh * 16 + l15;
            Ph[po] = bf2s(hb);
            Pl[po] = bf2s(lb);
        }
        __syncthreads();                       // P complete

        // gate partial: thread (seg=w, m=lane) sums 4 n-cols (hi+lo)
        {
            const short* ph = Ph + lane * PSS + w * 4;
            const short* pl = Pl + lane * PSS + w * 4;
#pragma unroll
            for (int u = 0; u < 4; u++) gacc += s2f(ph[u]) + s2f(pl[u]);
        }
        // PV: acc[m-tile, d] += P^T · CG  (A = P rows, B = CGt rows)
        bf16x8 pa = *(const bf16x8*)(Ph + (wm * 16 + l15) * PSS + quad * 8);
        bf16x8 pb = *(const bf16x8*)(Pl + (wm * 16 + l15) * PSS + quad * 8);
#pragma unroll
        for (int dt = 0; dt < 3; dt++) {
            bf16x8 bcg = *(const bf16x8*)(CGt + (wh * 48 + dt * 16 + l15) * PSS + quad * 8);
            acc[dt] = __builtin_amdgcn_mfma_f32_16x16x32_bf16(pa, bcg, acc[dt], 0, 0, 0);
            acc[dt] = __builtin_amdgcn_mfma_f32_16x16x32_bf16(pb, bcg, acc[dt], 0, 0, 0);
        }
        __syncthreads();                       // PV done before next stage
    }

    // epilogue: C/D layout col=lane&15, row=quad*4+reg
#pragma unroll
    for (int dt = 0; dt < 3; dt++)
#pragma unroll
        for (int r = 0; r < 4; r++) {
            int m = m0 + wm * 16 + quad * 4 + r;
            cbuf[((size_t)b * M_ + m) * C_ + h * D_ + wh * 48 + dt * 16 + l15] =
                __float2bfloat16(acc[dt][r]);
        }
    gred[w][lane] = gacc;
    __syncthreads();
    if (tid < 64) {
        float g = 0.f;
#pragma unroll
        for (int s = 0; s < 8; s++) g += gred[s][tid];
        gate[((size_t)b * H_ + h) * M_ + m0 + tid] = 1.f - g * (1.0f / N_);
    }
}

// ---------------- new_mem = LN(part0+part1+bias + gate*memh) -> mem_bf (+ ap, + d_out) ----------------
__global__ __launch_bounds__(256) void final_kernel(
    const float* __restrict__ part, const float* __restrict__ p_b2,
    const float* __restrict__ gate, const bf16* __restrict__ memh,
    const float* __restrict__ w, const float* __restrict__ bia,
    bf16* __restrict__ mem_bf, float* __restrict__ app, float* __restrict__ outp)
{
    __shared__ float sdata[256];
    int row = blockIdx.x;
    int b = row / M_, m = row % M_;
    float x[3];
    float sum = 0.f, sumsq = 0.f;
#pragma unroll
    for (int i = 0; i < 3; i++) {
        int c = threadIdx.x + i * 256;
        int h = c / D_;
        float v = part[(size_t)row * C_ + c] + part[(size_t)MP_ * C_ + (size_t)row * C_ + c]
                + p_b2[c]
                + gate[(b * H_ + h) * M_ + m] * b2f(memh[(size_t)row * C_ + c]);
        x[i] = v;
        sum += v; sumsq += v * v;
    }
    sum = block_reduce_sum256(sum, sdata);
    sumsq = block_reduce_sum256(sumsq, sdata);
    float mu = sum * (1.0f / C_);
    float var = sumsq * (1.0f / C_) - mu * mu;
    float rs = rsqrtf(var + 1e-5f);
#pragma unroll
    for (int i = 0; i < 3; i++) {
        int c = threadIdx.x + i * 256;
        float v = (x[i] - mu) * rs * w[c] + bia[c];
        bf16 hv = __float2bfloat16(v);
        mem_bf[(size_t)row * C_ + c] = hv;
        atomicAdd(&app[(size_t)b * C_ + c], b2f(hv));   // ap for next step
        if (outp) outp[(size_t)row * C_ + c] = v;
    }
}

extern "C" void kernel_launch(void* const* d_in, const int* in_sizes, int n_in,
                              void* d_out, int out_size, void* d_ws, size_t ws_size,
                              hipStream_t stream)
{
    const float* cur_fea = (const float*)d_in[0];
    const float* n1w = (const float*)d_in[1];
    const float* n1b = (const float*)d_in[2];
    const float* n2w = (const float*)d_in[3];
    const float* n2b = (const float*)d_in[4];
    const float* c_w1 = (const float*)d_in[5];
    const float* c_b1 = (const float*)d_in[6];
    const float* c_w2 = (const float*)d_in[7];
    const float* c_b2 = (const float*)d_in[8];
    const float* m_w1 = (const float*)d_in[9];
    const float* m_b1 = (const float*)d_in[10];
    const float* m_w2 = (const float*)d_in[11];
    const float* m_b2 = (const float*)d_in[12];
    const float* p_w1 = (const float*)d_in[13];
    const float* p_b1 = (const float*)d_in[14];
    const float* p_w2 = (const float*)d_in[15];
    const float* p_b2 = (const float*)d_in[16];
    const float* q_w = (const float*)d_in[17];
    const float* q_b = (const float*)d_in[18];
    const float* k_w = (const float*)d_in[19];
    const float* k_b = (const float*)d_in[20];

    // ---- workspace carve (256B-aligned) ----
    size_t off = 0;
    char* base = (char*)d_ws;
    auto carve = [&](size_t bytes) -> char* {
        char* r = base + off;
        off += (bytes + 255) & ~(size_t)255;
        return r;
    };
    bf16* cw1t = (bf16*)carve((size_t)HID_ * (2 * C_) * 2);
    bf16* cw2t = (bf16*)carve((size_t)C_ * HID_ * 2);
    bf16* mw1t = (bf16*)carve((size_t)HID_ * C_ * 2);
    bf16* mw2t = (bf16*)carve((size_t)C_ * HID_ * 2);
    bf16* pw1t = (bf16*)carve((size_t)HID_ * C_ * 2);
    bf16* pw2t = (bf16*)carve((size_t)C_ * HID_ * 2);
    bf16* qwt  = (bf16*)carve((size_t)C_ * C_ * 2);
    bf16* kwt  = (bf16*)carve((size_t)C_ * C_ * 2);
    bf16* mem_bf = (bf16*)carve((size_t)MP_ * C_ * 2);
    char* catreg = carve((size_t)MP_ * 2 * C_ * 2);           // cat; later qb|kb
    bf16* cat = (bf16*)catreg;
    bf16* qb  = (bf16*)catreg;                                // alias (cat dead after G1)
    bf16* kb  = (bf16*)catreg + (size_t)MP_ * C_;             // alias (fallback k-out)
    bf16* hid_c = (bf16*)carve((size_t)MP_ * HID_ * 2);       // c1/p1 out; cw2nt temp pre-loop
    char* hidm_reg = carve((size_t)MP_ * HID_ * 2);           // m1 out; p2 partials
    bf16*  hid_m = (bf16*)hidm_reg;
    float* part  = (float*)hidm_reg;
    bf16* cg    = (bf16*)carve((size_t)MP_ * C_ * 2);
    bf16* cbuf  = (bf16*)carve((size_t)MP_ * C_ * 2);
    bf16* memh  = (bf16*)carve((size_t)MP_ * C_ * 2);
    float* app0 = (float*)carve((size_t)B_ * C_ * 4);         // ap column sums (ping)
    float* app1 = (float*)carve((size_t)B_ * C_ * 4);         // ap column sums (pong)
    float* gateb = (float*)carve((size_t)B_ * H_ * M_ * 4);
    float* b2qb  = (float*)carve((size_t)C_ * 4);
    bf16* W2q_t = (bf16*)carve((size_t)C_ * HID_ * 2);
    const bool fuse_q = (off <= ws_size);
    bf16* kb2  = (bf16*)carve((size_t)MP_ * C_ * 2);          // dedicated k-out
    const bool fuse_k = (off <= ws_size);

    const dim3 blk(256);

    // ---- weight convert + transpose (single batched launch) ----
    {
        TEnts tds;
        tds.e[0] = { c_w1, cw1t, 2 * C_, HID_, (HID_ / 32) * ((2 * C_) / 32) };  // 4608
        tds.e[1] = { c_w2, cw2t, HID_, C_, (C_ / 32) * (HID_ / 32) };            // 2304
        tds.e[2] = { m_w1, mw1t, C_, HID_, (HID_ / 32) * (C_ / 32) };
        tds.e[3] = { m_w2, mw2t, HID_, C_, (C_ / 32) * (HID_ / 32) };
        tds.e[4] = { p_w1, pw1t, C_, HID_, (HID_ / 32) * (C_ / 32) };
        tds.e[5] = { p_w2, pw2t, HID_, C_, (C_ / 32) * (HID_ / 32) };
        tds.e[6] = { q_w, qwt, C_, C_, (C_ / 32) * (C_ / 32) };                  // 576
        tds.e[7] = { k_w, kwt, C_, C_, (C_ / 32) * (C_ / 32) };
        int total = 4608 + 2304 * 5 + 576 * 2;  // 17280
        transpose_all_kernel<<<total, blk, 0, stream>>>(tds);
    }

    if (fuse_q) {
        // W2q_t[n,j] = (c_w2 @ q_w)[j,n]: out = A @ Wt^T, A=qwt[768,768], Wt=cvt(c_w2)[3072,768]
        bf16* cw2nt = hid_c;   // temp, pre-loop only
        cvt_kernel<<<(HID_ * C_ + 255) / 256, blk, 0, stream>>>(c_w2, cw2nt, HID_ * C_);
        GemmDescs ds;
        ds.d[0] = { qwt, cw2nt, nullptr, W2q_t, C_, HID_, HID_ / 128, 0 };
        ds.d[1] = ds.d[0]; ds.d[2] = ds.d[0]; ds.d[3] = ds.d[0];
        mfma_gemm_multi<128><<<dim3(C_ / 128, HID_ / 128, 1), blk, 0, stream>>>(ds);
        b2q_kernel<<<C_, blk, 0, stream>>>(c_b2, q_b, W2q_t, b2qb);
    }

    // ---- init memory = LN(frame 0), with fused ap accumulation into app0 ----
    hipMemsetAsync(app0, 0, (size_t)B_ * C_ * 4, stream);
    ln_frame_kernel<<<ROWS_, blk, 0, stream>>>(cur_fea, 0, n1w, n1b, mem_bf, app0);

    for (int t = 1; t < T_; t++) {
        // app double-buffer: build_cat(t) reads cur and zeroes nxt in-kernel;
        // final(t) accumulates into nxt. No per-step memset dispatch.
        float* app_cur = ((t - 1) & 1) ? app1 : app0;
        float* app_nxt = (t & 1) ? app1 : app0;
        build_cat_kernel<<<ROWS_, blk, 0, stream>>>(cur_fea, t, n1w, n1b,
                                                    app_cur, app_nxt, cat);

        // G1: c1 + m1 (+ k when kb2 fits — k only needs mem_bf; dedicated
        // buffer avoids the cat-alias race). BN=128, dbuf: the proven config.
        {
            GemmDescs ds;
            ds.d[0] = { cat,    cw1t, c_b1, hid_c, 2 * C_, HID_, HID_ / 128, 1 };
            ds.d[1] = { mem_bf, mw1t, m_b1, hid_m, C_,     HID_, HID_ / 128, 1 };
            ds.d[2] = { mem_bf, kwt,  k_b,  kb2,   C_,     C_,   C_ / 128,   0 };
            ds.d[3] = ds.d[0];
            mfma_gemm_multi<128><<<dim3(MP_ / 128, HID_ / 128, fuse_k ? 3 : 2),
                                   blk, 0, stream>>>(ds);
        }
        // G2: c2 + m2 (+ k fallback) + fused q. cat dead after G1.
        {
            GemmDescs ds;
            int z = 0;
            ds.d[z++] = { hid_c,  cw2t, c_b2, cg,   HID_, C_, C_ / 64, 0 };
            ds.d[z++] = { hid_m,  mw2t, m_b2, memh, HID_, C_, C_ / 64, 0 };
            if (!fuse_k) ds.d[z++] = { mem_bf, kwt, k_b, kb, C_, C_, C_ / 64, 0 };
            if (fuse_q)  ds.d[z++] = { hid_c, W2q_t, b2qb, qb, HID_, C_, C_ / 64, 0 };
            for (int f = z; f < 4; f++) ds.d[f] = ds.d[0];
            mfma_gemm_multi<64><<<dim3(MP_ / 128, C_ / 64, z), blk, 0, stream>>>(ds);
        }
        if (!fuse_q) {
            GemmDescs ds;
            ds.d[0] = { cg, qwt, q_b, qb, C_, C_, C_ / 64, 0 };
            ds.d[1] = ds.d[0]; ds.d[2] = ds.d[0]; ds.d[3] = ds.d[0];
            mfma_gemm_multi<64><<<dim3(MP_ / 128, C_ / 64, 1), blk, 0, stream>>>(ds);
        }
        // fused MFMA attention + pool + gate (256 blocks, 8 waves)
        attn_mfma_kernel<<<dim3(4, H_, B_), dim3(512), 0, stream>>>(
            qb, fuse_k ? kb2 : kb, cg, cbuf, gateb);
        // p1 (BN=64: 624 blocks) into hid_c
        {
            GemmDescs ds;
            ds.d[0] = { cbuf, pw1t, p_b1, hid_c, C_, HID_, HID_ / 64, 1 };
            ds.d[1] = ds.d[0]; ds.d[2] = ds.d[0]; ds.d[3] = ds.d[0];
            mfma_gemm_multi<64><<<dim3(MP_ / 128, HID_ / 64, 1), blk, 0, stream>>>(ds);
        }
        // p2 split-K=2 -> fp32 partials (hidm_reg free: m1-out consumed by G2)
        mfma_gemm_splitk<<<dim3(MP_ / 128, C_ / 64, 2), blk, 0, stream>>>(hid_c, pw2t, part, HID_);
        // residual gate + LN -> new mem (+ fused ap accumulation into app_nxt)
        final_kernel<<<ROWS_, blk, 0, stream>>>(part, p_b2, gateb, memh, n2w, n2b,
                                                mem_bf, app_nxt,
                                                (t == T_ - 1) ? (float*)d_out : nullptr);
    }
}